// Round 9
// baseline (549.152 us; speedup 1.0000x reference)
//
#include <hip/hip_runtime.h>
#include <stdint.h>

// KronQRInjectedLinear: out = ((input @ rot) @ Q) @ R_eff.
// Kron structure: D via 4x2048^3 batched, rot via 2x4096x2048x2048 (see r4).
// GEMM core v7: 256x256 tile, 8 waves (2Mx4N), BK=32 chunks in 4 rotating
// buffers, ONE phase per chunk (16 MFMA 32x32x16, 12 ds_read_b128, 4 gloads,
// 2 barriers) -- half the sync points of v6. Proven-0-conflict LDS placement,
// compiler-managed lgkm waits, per-phase counted vmcnt(8), setprio, XCD swizzle.

typedef unsigned short u16;
typedef short bf16x8 __attribute__((ext_vector_type(8)));
typedef float f32x16 __attribute__((ext_vector_type(16)));

__device__ __forceinline__ u16 f2bf(float f) {
  union { float f; uint32_t u; } v; v.f = f;
  return (u16)((v.u + 0x7FFFu + ((v.u >> 16) & 1u)) >> 16);
}

__device__ __forceinline__ void store_out(float* p, float v) { *p = v; }
__device__ __forceinline__ void store_out(u16* p, float v) { *p = f2bf(v); }

__device__ __forceinline__ void gload_lds16(const u16* g, u16* l) {
  __builtin_amdgcn_global_load_lds(
      (__attribute__((address_space(1))) void*)(uintptr_t)g,
      (__attribute__((address_space(3))) void*)l, 16, 0, 0);
}

#define MFMA32(a, b, c) __builtin_amdgcn_mfma_f32_32x32x16_bf16((a), (b), (c), 0, 0, 0)

// ---------------- GEMM: C[M,N] = A[M,K] @ Bt[N,K]^T (batched on z) ----------------
// Piece (8KB) = 128 tile-rows x 32 kk, as 4 m-tiles x 2 ks x 8 LDS-rows:
//   block (r in 0..31 within m-tile, kblk b in 0..3): h=(r&15)>>1, q=(r>>4)&1, p=r&1,
//   ks=b>>1, b0=b&1 -> LDS row 16m+8ks+h, 16B-slot (2*b0+q+4*p)^h.
// Read lane l -> row 16m+8ks+((l&15)>>1), slot ((l>>4)+4(l&1))^((l&15)>>1)
//   == the proven conflict-free function (r8: SQ_LDS_BANK_CONFLICT = 0).
template <typename OutT>
__global__ __launch_bounds__(512, 2) void gemm256(
    const u16* __restrict__ A, const u16* __restrict__ Bt, OutT* __restrict__ C,
    int M, int N, int K, int ldC, long long sA, long long sC) {
  extern __shared__ __align__(16) u16 smem[];
  u16* ldsA = smem;           // 4 bufs x 8192 elems (64 KB)
  u16* ldsB = smem + 32768;

  const int tid  = (int)threadIdx.x;
  const int lane = tid & 63;
  const int wid  = tid >> 6;
  const int wr   = wid >> 2;       // 0..1 : M half (128 rows)
  const int wc   = wid & 3;        // 0..3 : N quarter (64 cols)

  // XCD-aware bijective swizzle (nwg % 8 == 0 for all our grids)
  const int tilesX = (int)gridDim.x;
  const int tilesXY = tilesX * (int)gridDim.y;
  const int nwg = tilesXY * (int)gridDim.z;
  const int bid = ((int)blockIdx.z * (int)gridDim.y + (int)blockIdx.y) * tilesX + (int)blockIdx.x;
  const int swz = (bid & 7) * (nwg >> 3) + (bid >> 3);
  const int z   = swz / tilesXY;
  const int rem = swz % tilesXY;
  const int brow = (rem / tilesX) << 8;
  const int bcol = (rem % tilesX) << 8;
  A += (size_t)z * sA;
  C += (size_t)z * sC;

  // fragment-read lane constants (proven-conflict-free address function)
  const int hh  = (lane & 15) >> 1;          // 0..7
  const int gq  = lane >> 4;                 // 0..3
  const int par = lane & 1;
  const int sfr = (((gq + 4 * par) ^ hh) << 3) + (hh << 6);   // elems within 1KB region
  const int abase = wr * 4096 + sfr;                          // + m*1024 + ks*512, + buf*8192
  const int bbase = (wc >> 1) * 4096 + (wc & 1) * 2048 + sfr; // + n*1024 + ks*512

  // staging: linear LDS dest (wid*1KB + lane*16B within piece); inverse-mapped source.
  const int Rw  = (wid << 3) + (lane >> 3);
  const int hS  = Rw & 7;
  const int xS  = (lane & 7) ^ hS;
  const int srow = ((Rw >> 4) << 5) + ((xS & 1) << 4) + (hS << 1) + (xS >> 2);
  const int scol = (((Rw >> 3) & 1) << 4) + (((xS >> 1) & 1) << 3);
  const size_t gA0 = (size_t)(brow + srow) * K + scol;
  const size_t gB0 = (size_t)(bcol + srow) * K + scol;
  const size_t rstep = (size_t)K << 7;     // 128 rows (piece rh stride)
  const int sdst = wid * 512;

  const int NC = K >> 5;                   // 32-wide chunks; NC % 4 == 0, NC >= 8

  f32x16 acc[4][2] = {};
  bf16x8 af[4][2], bf[2][2];

#define STG_A(c, rh) gload_lds16(A + gA0 + (rh) * rstep + (size_t)(c) * 32, \
    ldsA + ((c) & 3) * 8192 + (rh) * 4096 + sdst)
#define STG_B(c, rh) gload_lds16(Bt + gB0 + (rh) * rstep + (size_t)(c) * 32, \
    ldsB + ((c) & 3) * 8192 + (rh) * 4096 + sdst)
#define STAGE(c) do { STG_A(c, 0); STG_A(c, 1); STG_B(c, 0); STG_B(c, 1); } while (0)
#define VM8 asm volatile("s_waitcnt vmcnt(8)" ::: "memory")
#define VM4 asm volatile("s_waitcnt vmcnt(4)" ::: "memory")
#define VM0 asm volatile("s_waitcnt vmcnt(0)" ::: "memory")
#define NOPW (void)0

  // One phase per chunk (buf bb): 12 ds_reads (bf first) + stage -> barrier ->
  // 16 MFMA (compiler fine-grained lgkm waits) -> vmcnt -> barrier.
  // sched_barrier(0) at phase start pins reads below the producer barrier.
#define PH(bb, S, W) do {                                                       \
    __builtin_amdgcn_sched_barrier(0);                                          \
    const u16* _pa = ldsA + (bb) * 8192 + abase;                                \
    const u16* _pb = ldsB + (bb) * 8192 + bbase;                                \
    bf[0][0] = *(const bf16x8*)(_pb);                                           \
    bf[0][1] = *(const bf16x8*)(_pb + 512);                                     \
    bf[1][0] = *(const bf16x8*)(_pb + 1024);                                    \
    bf[1][1] = *(const bf16x8*)(_pb + 1536);                                    \
    af[0][0] = *(const bf16x8*)(_pa);                                           \
    af[0][1] = *(const bf16x8*)(_pa + 512);                                     \
    af[1][0] = *(const bf16x8*)(_pa + 1024);                                    \
    af[1][1] = *(const bf16x8*)(_pa + 1536);                                    \
    af[2][0] = *(const bf16x8*)(_pa + 2048);                                    \
    af[2][1] = *(const bf16x8*)(_pa + 2560);                                    \
    af[3][0] = *(const bf16x8*)(_pa + 3072);                                    \
    af[3][1] = *(const bf16x8*)(_pa + 3584);                                    \
    S;                                                                          \
    __builtin_amdgcn_s_barrier();                                               \
    __builtin_amdgcn_s_setprio(1);                                              \
    acc[0][0] = MFMA32(af[0][0], bf[0][0], acc[0][0]);                          \
    acc[0][0] = MFMA32(af[0][1], bf[0][1], acc[0][0]);                          \
    acc[0][1] = MFMA32(af[0][0], bf[1][0], acc[0][1]);                          \
    acc[0][1] = MFMA32(af[0][1], bf[1][1], acc[0][1]);                          \
    acc[1][0] = MFMA32(af[1][0], bf[0][0], acc[1][0]);                          \
    acc[1][0] = MFMA32(af[1][1], bf[0][1], acc[1][0]);                          \
    acc[1][1] = MFMA32(af[1][0], bf[1][0], acc[1][1]);                          \
    acc[1][1] = MFMA32(af[1][1], bf[1][1], acc[1][1]);                          \
    acc[2][0] = MFMA32(af[2][0], bf[0][0], acc[2][0]);                          \
    acc[2][0] = MFMA32(af[2][1], bf[0][1], acc[2][0]);                          \
    acc[2][1] = MFMA32(af[2][0], bf[1][0], acc[2][1]);                          \
    acc[2][1] = MFMA32(af[2][1], bf[1][1], acc[2][1]);                          \
    acc[3][0] = MFMA32(af[3][0], bf[0][0], acc[3][0]);                          \
    acc[3][0] = MFMA32(af[3][1], bf[0][1], acc[3][0]);                          \
    acc[3][1] = MFMA32(af[3][0], bf[1][0], acc[3][1]);                          \
    acc[3][1] = MFMA32(af[3][1], bf[1][1], acc[3][1]);                          \
    __builtin_amdgcn_s_setprio(0);                                              \
    W;                                                                          \
    __builtin_amdgcn_s_barrier();                                               \
  } while (0)

  // Prologue: chunks 0,1,2 staged; drain chunk 0, leave {1,2} (8 loads) in flight.
  STAGE(0); STAGE(1); STAGE(2);
  VM8;
  __builtin_amdgcn_s_barrier();

  // Steady state: phase c stages chunk c+3; vmcnt(8) drains chunk c+1 each phase.
  for (int c = 0; c + 4 < NC; c += 4) {
    PH(0, STAGE(c + 3), VM8);
    PH(1, STAGE(c + 4), VM8);
    PH(2, STAGE(c + 5), VM8);
    PH(3, STAGE(c + 6), VM8);
  }
  // Tail: phases NC-4..NC-1 (bufs 0..3 since NC%4==0); drain 8 -> 4 -> 0.
  PH(0, STAGE(NC - 1), VM8);
  PH(1, NOPW, VM4);
  PH(2, NOPW, VM0);
  PH(3, NOPW, NOPW);

#undef PH
#undef STAGE
#undef STG_A
#undef STG_B
#undef VM8
#undef VM4
#undef VM0
#undef NOPW

  // C/D 32x32 layout: col = lane&31, row = (reg&3) + 8*(reg>>2) + 4*(lane>>5)
  const int l31 = lane & 31;
  const int lg2 = lane >> 5;
#pragma unroll
  for (int m = 0; m < 4; ++m) {
    const int rb = brow + wr * 128 + m * 32 + 4 * lg2;
#pragma unroll
    for (int n = 0; n < 2; ++n) {
      const int cc = bcol + wc * 64 + n * 32 + l31;
#pragma unroll
      for (int q = 0; q < 4; ++q)
#pragma unroll
        for (int j = 0; j < 4; ++j)
          store_out(&C[(size_t)(rb + 8 * q + j) * ldC + cc], acc[m][n][q * 4 + j]);
    }
  }
}

// ---------------- tiled transpose: out[c][r] = bf16(in[r][c]) ----------------
__global__ void trans_kernel(const float* __restrict__ in, u16* __restrict__ out, int n) {
  __shared__ float t[32][33];
  const int bx = (int)blockIdx.x * 32, by = (int)blockIdx.y * 32;
  const int x = (int)threadIdx.x, y0 = (int)threadIdx.y;
#pragma unroll
  for (int dy = 0; dy < 32; dy += 8)
    t[y0 + dy][x] = in[(size_t)(bx + y0 + dy) * n + by + x];
  __syncthreads();
#pragma unroll
  for (int dy = 0; dy < 32; dy += 8)
    out[(size_t)(by + y0 + dy) * n + bx + x] = f2bf(t[x][y0 + dy]);
}

// Qtp[c][perm(r)] = bf16(Q[r][c]); perm(r) = ((r&1)<<11)|(r>>1)
__global__ void transperm_kernel(const float* __restrict__ in, u16* __restrict__ out) {
  __shared__ float t[32][33];
  const int bx = (int)blockIdx.x * 32, by = (int)blockIdx.y * 32;
  const int x = (int)threadIdx.x, y0 = (int)threadIdx.y;
#pragma unroll
  for (int dy = 0; dy < 32; dy += 8)
    t[y0 + dy][x] = in[(size_t)(bx + y0 + dy) * 4096 + by + x];
  __syncthreads();
  const int r = bx + x;
  const int cp = ((r & 1) << 11) | (r >> 1);
#pragma unroll
  for (int dy = 0; dy < 32; dy += 8)
    out[(size_t)(by + y0 + dy) * 4096 + cp] = f2bf(t[x][y0 + dy]);
}

// rteff[i][j] = bf16(R[j][i] + D[i][j]); D[i][j] = Dsub[(i&1)*2+(j&1)][i>>1][j>>1]
__global__ void transadd_kernel(const float* __restrict__ R, const float* __restrict__ Dsub,
                                u16* __restrict__ out) {
  __shared__ float t[32][33];
  const int bx = (int)blockIdx.x * 32, by = (int)blockIdx.y * 32;
  const int x = (int)threadIdx.x, y0 = (int)threadIdx.y;
#pragma unroll
  for (int dy = 0; dy < 32; dy += 8)
    t[y0 + dy][x] = R[(size_t)(bx + y0 + dy) * 4096 + by + x];
  __syncthreads();
  const int j = bx + x;
#pragma unroll
  for (int dy = 0; dy < 32; dy += 8) {
    const int i = by + y0 + dy;
    const int s = ((i & 1) << 1) | (j & 1);
    const float d = Dsub[(size_t)s * 4194304 + ((size_t)(i >> 1) << 11) + (j >> 1)];
    out[(size_t)i * 4096 + j] = f2bf(t[x][y0 + dy] + d);
  }
}

// R1bf = bf16(R1); Asc[s][i1][k1] = bf16(R1[i1][k1] * g_s[k1])
__global__ void scale_r1_kernel(const float* __restrict__ R1, const float* __restrict__ R2,
                                const float* __restrict__ lam,
                                u16* __restrict__ R1bf, u16* __restrict__ Asc) {
  const int idx = (int)blockIdx.x * 256 + (int)threadIdx.x;   // over 2048*512
  const int i1 = idx >> 9, k1 = (idx & 511) << 2;
  const float4 r1 = *(const float4*)(R1 + (size_t)i1 * 2048 + k1);
  const float4 l0 = *(const float4*)(lam + 2 * k1);
  const float4 l1 = *(const float4*)(lam + 2 * k1 + 4);
  const float le[4] = {l0.x, l0.z, l1.x, l1.z};
  const float lo[4] = {l0.y, l0.w, l1.y, l1.w};
  const float rv[4] = {r1.x, r1.y, r1.z, r1.w};
  ushort4 rb;
  rb.x = f2bf(r1.x); rb.y = f2bf(r1.y); rb.z = f2bf(r1.z); rb.w = f2bf(r1.w);
  *(ushort4*)(R1bf + (size_t)i1 * 2048 + k1) = rb;
#pragma unroll
  for (int s = 0; s < 4; ++s) {
    const int i2 = s >> 1, j2 = s & 1;
    const float c0 = R2[i2 * 2] * R2[j2 * 2];
    const float c1 = R2[i2 * 2 + 1] * R2[j2 * 2 + 1];
    ushort4 o;
    u16* dst = Asc + (size_t)s * 4194304 + (size_t)i1 * 2048 + k1;
    o.x = f2bf(rv[0] * (le[0] * c0 + lo[0] * c1));
    o.y = f2bf(rv[1] * (le[1] * c0 + lo[1] * c1));
    o.z = f2bf(rv[2] * (le[2] * c0 + lo[2] * c1));
    o.w = f2bf(rv[3] * (le[3] * c0 + lo[3] * c1));
    *(ushort4*)dst = o;
  }
}

// T[j2][s][k1] = bf16(in[s][2k1]*Q2[0][j2] + in[s][2k1+1]*Q2[1][j2])
__global__ void tprep_kernel(const float* __restrict__ in, const float* __restrict__ Q2,
                             u16* __restrict__ T) {
  const int idx = (int)blockIdx.x * 256 + (int)threadIdx.x;   // over 4096*512
  const int s = idx >> 9, k1 = (idx & 511) << 2;
  const float4 a = *(const float4*)(in + (size_t)s * 4096 + 2 * k1);
  const float4 b = *(const float4*)(in + (size_t)s * 4096 + 2 * k1 + 4);
  const float e[4] = {a.x, a.z, b.x, b.z};
  const float o[4] = {a.y, a.w, b.y, b.w};
  const float q00 = Q2[0], q01 = Q2[1], q10 = Q2[2], q11 = Q2[3];
  ushort4 t0, t1;
  t0.x = f2bf(e[0] * q00 + o[0] * q10); t1.x = f2bf(e[0] * q01 + o[0] * q11);
  t0.y = f2bf(e[1] * q00 + o[1] * q10); t1.y = f2bf(e[1] * q01 + o[1] * q11);
  t0.z = f2bf(e[2] * q00 + o[2] * q10); t1.z = f2bf(e[2] * q01 + o[2] * q11);
  t0.w = f2bf(e[3] * q00 + o[3] * q10); t1.w = f2bf(e[3] * q01 + o[3] * q11);
  *(ushort4*)(T + (size_t)s * 2048 + k1) = t0;
  *(ushort4*)(T + 8388608 + (size_t)s * 2048 + k1) = t1;
}

extern "C" void kernel_launch(void* const* d_in, const int* in_sizes, int n_in,
                              void* d_out, int out_size, void* d_ws, size_t ws_size,
                              hipStream_t stream) {
  const float* input = (const float*)d_in[0];
  const float* Q     = (const float*)d_in[1];
  const float* R     = (const float*)d_in[2];
  const float* Q1    = (const float*)d_in[3];
  const float* Q2    = (const float*)d_in[4];
  const float* R1    = (const float*)d_in[5];
  const float* R2    = (const float*)d_in[6];
  const float* lam   = (const float*)d_in[7];
  float* out = (float*)d_out;

  const size_t MB = 1024ull * 1024ull;
  char* ws = (char*)d_ws;
  u16* R1bf  = (u16*)(ws + 0 * MB);
  u16* Asc   = (u16*)(ws + 8 * MB);     // 4 planes of 8MB; reused as X2 later
  u16* Q1tb  = (u16*)(ws + 40 * MB);
  u16* T     = (u16*)(ws + 48 * MB);    // 2 planes of 16MB
  u16* Qtp   = (u16*)(ws + 80 * MB);
  u16* rteff = (u16*)(ws + 112 * MB);
  u16* X1p   = (u16*)(ws + 144 * MB);   // needs ws_size >= 176 MB
  u16* X2    = Asc;
  float* Dsub = (float*)d_out;          // 4 x 2048^2 f32, consumed by transadd

  {
    void (*pf)(const u16*, const u16*, float*, int, int, int, int, long long, long long) = gemm256<float>;
    void (*pb)(const u16*, const u16*, u16*, int, int, int, int, long long, long long)   = gemm256<u16>;
    (void)hipFuncSetAttribute((const void*)pf, hipFuncAttributeMaxDynamicSharedMemorySize, 131072);
    (void)hipFuncSetAttribute((const void*)pb, hipFuncAttributeMaxDynamicSharedMemorySize, 131072);
  }

  const dim3 tb(32, 8);
  // 1) Q1tb = bf16(Q1^T)
  trans_kernel<<<dim3(64, 64), tb, 0, stream>>>(Q1, Q1tb, 2048);
  // 2) Qtp = permuted bf16(Q^T)
  transperm_kernel<<<dim3(128, 128), tb, 0, stream>>>(Q, Qtp);
  // 3) R1bf + scaled copies Asc[s]
  scale_r1_kernel<<<4096, 256, 0, stream>>>(R1, R2, lam, R1bf, Asc);
  // 4) T[j2] = Q2-contraction of input
  tprep_kernel<<<8192, 256, 0, stream>>>(input, Q2, T);
  // 5) Dsub[s] = Asc[s] @ R1bf^T   (batched 4 x 2048^3)
  gemm256<float><<<dim3(8, 8, 4), 512, 131072, stream>>>(
      Asc, R1bf, Dsub, 2048, 2048, 2048, 2048, 4194304LL, 4194304LL);
  // 6) rteff = R^T + D
  transadd_kernel<<<dim3(128, 128), tb, 0, stream>>>(R, Dsub, rteff);
  // 7) X1p[:, j2*2048+j1] = T[j2] @ Q1tb^T   (batched 2 x 4096x2048x2048)
  gemm256<u16><<<dim3(8, 16, 2), 512, 131072, stream>>>(
      T, Q1tb, X1p, 4096, 2048, 2048, 4096, 8388608LL, 2048LL);
  // 8) X2 = X1p @ Qtp^T   (4096^3)
  gemm256<u16><<<dim3(16, 16, 1), 512, 131072, stream>>>(
      X1p, Qtp, X2, 4096, 4096, 4096, 4096, 0LL, 0LL);
  // 9) out = X2 @ rteff^T  (4096^3, f32)
  gemm256<float><<<dim3(16, 16, 1), 512, 131072, stream>>>(
      X2, rteff, out, 4096, 4096, 4096, 4096, 0LL, 0LL);
}

// Round 10
// 523.904 us; speedup vs baseline: 1.0482x; 1.0482x over previous
//
#include <hip/hip_runtime.h>
#include <stdint.h>

// KronQRInjectedLinear: out = ((input @ rot) @ Q) @ R_eff.
// Kron structure: D via 4x2048^3 batched, rot via 2x4096x2048x2048 (see r4).
// GEMM core v8: 256x256 tile, 8 waves (2Mx4N), BK=32 chunks in 4 rotating
// buffers, 32x32x16 MFMA, REGISTER-DOUBLE-BUFFERED A-frags so chunk c+1's
// ds_reads overlap chunk c's MFMA cluster (r9 showed reads+MFMA were
// serialized by lgkmcnt(0); this removes it). Proven-0-conflict swizzle,
// counted vmcnt, end-of-phase lgkm drain for DMA-WAR safety, setprio, XCD swz.

typedef unsigned short u16;
typedef short bf16x8 __attribute__((ext_vector_type(8)));
typedef float f32x16 __attribute__((ext_vector_type(16)));

__device__ __forceinline__ u16 f2bf(float f) {
  union { float f; uint32_t u; } v; v.f = f;
  return (u16)((v.u + 0x7FFFu + ((v.u >> 16) & 1u)) >> 16);
}

__device__ __forceinline__ void store_out(float* p, float v) { *p = v; }
__device__ __forceinline__ void store_out(u16* p, float v) { *p = f2bf(v); }

__device__ __forceinline__ void gload_lds16(const u16* g, u16* l) {
  __builtin_amdgcn_global_load_lds(
      (__attribute__((address_space(1))) void*)(uintptr_t)g,
      (__attribute__((address_space(3))) void*)l, 16, 0, 0);
}

#define MFMA32(a, b, c) __builtin_amdgcn_mfma_f32_32x32x16_bf16((a), (b), (c), 0, 0, 0)

// ---------------- GEMM: C[M,N] = A[M,K] @ Bt[N,K]^T (batched on z) ----------------
// LDS piece layout + proven-conflict-free read function: see r8 (conflicts == 0).
template <typename OutT>
__global__ __launch_bounds__(512, 2) void gemm256(
    const u16* __restrict__ A, const u16* __restrict__ Bt, OutT* __restrict__ C,
    int M, int N, int K, int ldC, long long sA, long long sC) {
  extern __shared__ __align__(16) u16 smem[];
  u16* ldsA = smem;           // 4 bufs x 8192 elems (64 KB)
  u16* ldsB = smem + 32768;

  const int tid  = (int)threadIdx.x;
  const int lane = tid & 63;
  const int wid  = tid >> 6;
  const int wr   = wid >> 2;       // 0..1 : M half (128 rows)
  const int wc   = wid & 3;        // 0..3 : N quarter (64 cols)

  // XCD-aware bijective swizzle (nwg % 8 == 0 for all our grids)
  const int tilesX = (int)gridDim.x;
  const int tilesXY = tilesX * (int)gridDim.y;
  const int nwg = tilesXY * (int)gridDim.z;
  const int bid = ((int)blockIdx.z * (int)gridDim.y + (int)blockIdx.y) * tilesX + (int)blockIdx.x;
  const int swz = (bid & 7) * (nwg >> 3) + (bid >> 3);
  const int z   = swz / tilesXY;
  const int rem = swz % tilesXY;
  const int brow = (rem / tilesX) << 8;
  const int bcol = (rem % tilesX) << 8;
  A += (size_t)z * sA;
  C += (size_t)z * sC;

  // fragment-read lane constants (proven-conflict-free address function, r8)
  const int hh  = (lane & 15) >> 1;          // 0..7
  const int gq  = lane >> 4;                 // 0..3
  const int par = lane & 1;
  const int sfr = (((gq + 4 * par) ^ hh) << 3) + (hh << 6);   // elems within 1KB region
  const int abase = wr * 4096 + sfr;                          // + m*1024 + ks*512, + buf*8192
  const int bbase = (wc >> 1) * 4096 + (wc & 1) * 2048 + sfr; // + n*1024 + ks*512

  // staging: linear LDS dest (wid*1KB + lane*16B within piece); inverse-mapped source.
  const int Rw  = (wid << 3) + (lane >> 3);
  const int hS  = Rw & 7;
  const int xS  = (lane & 7) ^ hS;
  const int srow = ((Rw >> 4) << 5) + ((xS & 1) << 4) + (hS << 1) + (xS >> 2);
  const int scol = (((Rw >> 3) & 1) << 4) + (((xS >> 1) & 1) << 3);
  const size_t gA0 = (size_t)(brow + srow) * K + scol;
  const size_t gB0 = (size_t)(bcol + srow) * K + scol;
  const size_t rstep = (size_t)K << 7;     // 128 rows (piece rh stride)
  const int sdst = wid * 512;

  const int NC = K >> 5;                   // 32-wide chunks; NC % 4 == 0, NC >= 8

  f32x16 acc[4][2] = {};
  bf16x8 fA0[4][2], fA1[4][2], fb[2][2];

#define STG_A(c, rh) gload_lds16(A + gA0 + (rh) * rstep + (size_t)(c) * 32, \
    ldsA + ((c) & 3) * 8192 + (rh) * 4096 + sdst)
#define STG_B(c, rh) gload_lds16(Bt + gB0 + (rh) * rstep + (size_t)(c) * 32, \
    ldsB + ((c) & 3) * 8192 + (rh) * 4096 + sdst)
#define STAGE(c) do { STG_A(c, 0); STG_A(c, 1); STG_B(c, 0); STG_B(c, 1); } while (0)
#define VM12 asm volatile("s_waitcnt vmcnt(12)" ::: "memory")
#define VM8  asm volatile("s_waitcnt vmcnt(8)" ::: "memory")
#define VM4  asm volatile("s_waitcnt vmcnt(4)" ::: "memory")
#define VM0  asm volatile("s_waitcnt vmcnt(0)" ::: "memory")
#define NOPW (void)0

#define RD_A(DST, BN) do {                                                      \
    const u16* _pa = ldsA + (BN) * 8192 + abase;                                \
    DST[0][0] = *(const bf16x8*)(_pa);                                          \
    DST[0][1] = *(const bf16x8*)(_pa + 512);                                    \
    DST[1][0] = *(const bf16x8*)(_pa + 1024);                                   \
    DST[1][1] = *(const bf16x8*)(_pa + 1536);                                   \
    DST[2][0] = *(const bf16x8*)(_pa + 2048);                                   \
    DST[2][1] = *(const bf16x8*)(_pa + 2560);                                   \
    DST[3][0] = *(const bf16x8*)(_pa + 3072);                                   \
    DST[3][1] = *(const bf16x8*)(_pa + 3584);                                   \
  } while (0)

#define RD_B(BC) do {                                                           \
    const u16* _pb = ldsB + (BC) * 8192 + bbase;                                \
    fb[0][0] = *(const bf16x8*)(_pb);                                           \
    fb[0][1] = *(const bf16x8*)(_pb + 512);                                     \
    fb[1][0] = *(const bf16x8*)(_pb + 1024);                                    \
    fb[1][1] = *(const bf16x8*)(_pb + 1536);                                    \
  } while (0)

#define MM(CUR) do {                                                            \
    __builtin_amdgcn_s_setprio(1);                                              \
    acc[0][0] = MFMA32(CUR[0][0], fb[0][0], acc[0][0]);                         \
    acc[0][0] = MFMA32(CUR[0][1], fb[0][1], acc[0][0]);                         \
    acc[0][1] = MFMA32(CUR[0][0], fb[1][0], acc[0][1]);                         \
    acc[0][1] = MFMA32(CUR[0][1], fb[1][1], acc[0][1]);                         \
    acc[1][0] = MFMA32(CUR[1][0], fb[0][0], acc[1][0]);                         \
    acc[1][0] = MFMA32(CUR[1][1], fb[0][1], acc[1][0]);                         \
    acc[1][1] = MFMA32(CUR[1][0], fb[1][0], acc[1][1]);                         \
    acc[1][1] = MFMA32(CUR[1][1], fb[1][1], acc[1][1]);                         \
    acc[2][0] = MFMA32(CUR[2][0], fb[0][0], acc[2][0]);                         \
    acc[2][0] = MFMA32(CUR[2][1], fb[0][1], acc[2][0]);                         \
    acc[2][1] = MFMA32(CUR[2][0], fb[1][0], acc[2][1]);                         \
    acc[2][1] = MFMA32(CUR[2][1], fb[1][1], acc[2][1]);                         \
    acc[3][0] = MFMA32(CUR[3][0], fb[0][0], acc[3][0]);                         \
    acc[3][0] = MFMA32(CUR[3][1], fb[0][1], acc[3][0]);                         \
    acc[3][1] = MFMA32(CUR[3][0], fb[1][0], acc[3][1]);                         \
    acc[3][1] = MFMA32(CUR[3][1], fb[1][1], acc[3][1]);                         \
    __builtin_amdgcn_s_setprio(0);                                              \
  } while (0)

  // Phase c: compute chunk c from CUR (read last phase); read B(c) [4] + A(c+1)
  // [8, into OTH, overlapping MFMA]; lgkm(8) drains only B before STAGE (DMA-WAR);
  // end lgkm(0)+barrier closes the read window before next phase's DMA.
#define PH(CUR, OTH, BC, BN, DORD, DOSTG, c4, W) do {                           \
    W;                                                                          \
    __builtin_amdgcn_s_barrier();                                               \
    __builtin_amdgcn_sched_barrier(0);                                          \
    RD_B(BC);                                                                   \
    if (DORD) RD_A(OTH, BN);                                                    \
    asm volatile("s_waitcnt lgkmcnt(8)" ::: "memory");                          \
    __builtin_amdgcn_sched_barrier(0);                                          \
    if (DOSTG) STAGE(c4);                                                       \
    MM(CUR);                                                                    \
    asm volatile("s_waitcnt lgkmcnt(0)" ::: "memory");                          \
    __builtin_amdgcn_sched_barrier(0);                                          \
    __builtin_amdgcn_s_barrier();                                               \
  } while (0)

  // Prologue: stage chunks 0..3; drain chunk 0; preload A(0) into fA0.
  STAGE(0); STAGE(1); STAGE(2); STAGE(3);
  VM12;
  __builtin_amdgcn_sched_barrier(0);
  __builtin_amdgcn_s_barrier();
  __builtin_amdgcn_sched_barrier(0);
  RD_A(fA0, 0);
  asm volatile("s_waitcnt lgkmcnt(0)" ::: "memory");
  __builtin_amdgcn_sched_barrier(0);

  for (int c = 0; c + 4 < NC; c += 4) {
    PH(fA0, fA1, 0, 1, 1, 1, c + 4, VM8);
    PH(fA1, fA0, 1, 2, 1, 1, c + 5, VM8);
    PH(fA0, fA1, 2, 3, 1, 1, c + 6, VM8);
    PH(fA1, fA0, 3, 0, 1, 1, c + 7, VM8);
  }
  // Tail: chunks NC-4..NC-1; drain 8 -> 4 -> 0; last phase has no A-read/stage.
  PH(fA0, fA1, 0, 1, 1, 0, 0, VM8);
  PH(fA1, fA0, 1, 2, 1, 0, 0, VM4);
  PH(fA0, fA1, 2, 3, 1, 0, 0, VM0);
  PH(fA1, fA0, 3, 0, 0, 0, 0, NOPW);

#undef PH
#undef MM
#undef RD_A
#undef RD_B
#undef STAGE
#undef STG_A
#undef STG_B
#undef VM12
#undef VM8
#undef VM4
#undef VM0
#undef NOPW

  // C/D 32x32 layout: col = lane&31, row = (reg&3) + 8*(reg>>2) + 4*(lane>>5)
  const int l31 = lane & 31;
  const int lg2 = lane >> 5;
#pragma unroll
  for (int m = 0; m < 4; ++m) {
    const int rb = brow + wr * 128 + m * 32 + 4 * lg2;
#pragma unroll
    for (int n = 0; n < 2; ++n) {
      const int cc = bcol + wc * 64 + n * 32 + l31;
#pragma unroll
      for (int q = 0; q < 4; ++q)
#pragma unroll
        for (int j = 0; j < 4; ++j)
          store_out(&C[(size_t)(rb + 8 * q + j) * ldC + cc], acc[m][n][q * 4 + j]);
    }
  }
}

// ---------------- tiled transpose: out[c][r] = bf16(in[r][c]) ----------------
__global__ void trans_kernel(const float* __restrict__ in, u16* __restrict__ out, int n) {
  __shared__ float t[32][33];
  const int bx = (int)blockIdx.x * 32, by = (int)blockIdx.y * 32;
  const int x = (int)threadIdx.x, y0 = (int)threadIdx.y;
#pragma unroll
  for (int dy = 0; dy < 32; dy += 8)
    t[y0 + dy][x] = in[(size_t)(bx + y0 + dy) * n + by + x];
  __syncthreads();
#pragma unroll
  for (int dy = 0; dy < 32; dy += 8)
    out[(size_t)(by + y0 + dy) * n + bx + x] = f2bf(t[x][y0 + dy]);
}

// Qtp[c][perm(r)] = bf16(Q[r][c]); perm(r) = ((r&1)<<11)|(r>>1)
__global__ void transperm_kernel(const float* __restrict__ in, u16* __restrict__ out) {
  __shared__ float t[32][33];
  const int bx = (int)blockIdx.x * 32, by = (int)blockIdx.y * 32;
  const int x = (int)threadIdx.x, y0 = (int)threadIdx.y;
#pragma unroll
  for (int dy = 0; dy < 32; dy += 8)
    t[y0 + dy][x] = in[(size_t)(bx + y0 + dy) * 4096 + by + x];
  __syncthreads();
  const int r = bx + x;
  const int cp = ((r & 1) << 11) | (r >> 1);
#pragma unroll
  for (int dy = 0; dy < 32; dy += 8)
    out[(size_t)(by + y0 + dy) * 4096 + cp] = f2bf(t[x][y0 + dy]);
}

// rteff[i][j] = bf16(R[j][i] + D[i][j]); D[i][j] = Dsub[(i&1)*2+(j&1)][i>>1][j>>1]
__global__ void transadd_kernel(const float* __restrict__ R, const float* __restrict__ Dsub,
                                u16* __restrict__ out) {
  __shared__ float t[32][33];
  const int bx = (int)blockIdx.x * 32, by = (int)blockIdx.y * 32;
  const int x = (int)threadIdx.x, y0 = (int)threadIdx.y;
#pragma unroll
  for (int dy = 0; dy < 32; dy += 8)
    t[y0 + dy][x] = R[(size_t)(bx + y0 + dy) * 4096 + by + x];
  __syncthreads();
  const int j = bx + x;
#pragma unroll
  for (int dy = 0; dy < 32; dy += 8) {
    const int i = by + y0 + dy;
    const int s = ((i & 1) << 1) | (j & 1);
    const float d = Dsub[(size_t)s * 4194304 + ((size_t)(i >> 1) << 11) + (j >> 1)];
    out[(size_t)i * 4096 + j] = f2bf(t[x][y0 + dy] + d);
  }
}

// R1bf = bf16(R1); Asc[s][i1][k1] = bf16(R1[i1][k1] * g_s[k1])
__global__ void scale_r1_kernel(const float* __restrict__ R1, const float* __restrict__ R2,
                                const float* __restrict__ lam,
                                u16* __restrict__ R1bf, u16* __restrict__ Asc) {
  const int idx = (int)blockIdx.x * 256 + (int)threadIdx.x;   // over 2048*512
  const int i1 = idx >> 9, k1 = (idx & 511) << 2;
  const float4 r1 = *(const float4*)(R1 + (size_t)i1 * 2048 + k1);
  const float4 l0 = *(const float4*)(lam + 2 * k1);
  const float4 l1 = *(const float4*)(lam + 2 * k1 + 4);
  const float le[4] = {l0.x, l0.z, l1.x, l1.z};
  const float lo[4] = {l0.y, l0.w, l1.y, l1.w};
  const float rv[4] = {r1.x, r1.y, r1.z, r1.w};
  ushort4 rb;
  rb.x = f2bf(r1.x); rb.y = f2bf(r1.y); rb.z = f2bf(r1.z); rb.w = f2bf(r1.w);
  *(ushort4*)(R1bf + (size_t)i1 * 2048 + k1) = rb;
#pragma unroll
  for (int s = 0; s < 4; ++s) {
    const int i2 = s >> 1, j2 = s & 1;
    const float c0 = R2[i2 * 2] * R2[j2 * 2];
    const float c1 = R2[i2 * 2 + 1] * R2[j2 * 2 + 1];
    ushort4 o;
    u16* dst = Asc + (size_t)s * 4194304 + (size_t)i1 * 2048 + k1;
    o.x = f2bf(rv[0] * (le[0] * c0 + lo[0] * c1));
    o.y = f2bf(rv[1] * (le[1] * c0 + lo[1] * c1));
    o.z = f2bf(rv[2] * (le[2] * c0 + lo[2] * c1));
    o.w = f2bf(rv[3] * (le[3] * c0 + lo[3] * c1));
    *(ushort4*)dst = o;
  }
}

// T[j2][s][k1] = bf16(in[s][2k1]*Q2[0][j2] + in[s][2k1+1]*Q2[1][j2])
__global__ void tprep_kernel(const float* __restrict__ in, const float* __restrict__ Q2,
                             u16* __restrict__ T) {
  const int idx = (int)blockIdx.x * 256 + (int)threadIdx.x;   // over 4096*512
  const int s = idx >> 9, k1 = (idx & 511) << 2;
  const float4 a = *(const float4*)(in + (size_t)s * 4096 + 2 * k1);
  const float4 b = *(const float4*)(in + (size_t)s * 4096 + 2 * k1 + 4);
  const float e[4] = {a.x, a.z, b.x, b.z};
  const float o[4] = {a.y, a.w, b.y, b.w};
  const float q00 = Q2[0], q01 = Q2[1], q10 = Q2[2], q11 = Q2[3];
  ushort4 t0, t1;
  t0.x = f2bf(e[0] * q00 + o[0] * q10); t1.x = f2bf(e[0] * q01 + o[0] * q11);
  t0.y = f2bf(e[1] * q00 + o[1] * q10); t1.y = f2bf(e[1] * q01 + o[1] * q11);
  t0.z = f2bf(e[2] * q00 + o[2] * q10); t1.z = f2bf(e[2] * q01 + o[2] * q11);
  t0.w = f2bf(e[3] * q00 + o[3] * q10); t1.w = f2bf(e[3] * q01 + o[3] * q11);
  *(ushort4*)(T + (size_t)s * 2048 + k1) = t0;
  *(ushort4*)(T + 8388608 + (size_t)s * 2048 + k1) = t1;
}

extern "C" void kernel_launch(void* const* d_in, const int* in_sizes, int n_in,
                              void* d_out, int out_size, void* d_ws, size_t ws_size,
                              hipStream_t stream) {
  const float* input = (const float*)d_in[0];
  const float* Q     = (const float*)d_in[1];
  const float* R     = (const float*)d_in[2];
  const float* Q1    = (const float*)d_in[3];
  const float* Q2    = (const float*)d_in[4];
  const float* R1    = (const float*)d_in[5];
  const float* R2    = (const float*)d_in[6];
  const float* lam   = (const float*)d_in[7];
  float* out = (float*)d_out;

  const size_t MB = 1024ull * 1024ull;
  char* ws = (char*)d_ws;
  u16* R1bf  = (u16*)(ws + 0 * MB);
  u16* Asc   = (u16*)(ws + 8 * MB);     // 4 planes of 8MB; reused as X2 later
  u16* Q1tb  = (u16*)(ws + 40 * MB);
  u16* T     = (u16*)(ws + 48 * MB);    // 2 planes of 16MB
  u16* Qtp   = (u16*)(ws + 80 * MB);
  u16* rteff = (u16*)(ws + 112 * MB);
  u16* X1p   = (u16*)(ws + 144 * MB);   // needs ws_size >= 176 MB
  u16* X2    = Asc;
  float* Dsub = (float*)d_out;          // 4 x 2048^2 f32, consumed by transadd

  {
    void (*pf)(const u16*, const u16*, float*, int, int, int, int, long long, long long) = gemm256<float>;
    void (*pb)(const u16*, const u16*, u16*, int, int, int, int, long long, long long)   = gemm256<u16>;
    (void)hipFuncSetAttribute((const void*)pf, hipFuncAttributeMaxDynamicSharedMemorySize, 131072);
    (void)hipFuncSetAttribute((const void*)pb, hipFuncAttributeMaxDynamicSharedMemorySize, 131072);
  }

  const dim3 tb(32, 8);
  // 1) Q1tb = bf16(Q1^T)
  trans_kernel<<<dim3(64, 64), tb, 0, stream>>>(Q1, Q1tb, 2048);
  // 2) Qtp = permuted bf16(Q^T)
  transperm_kernel<<<dim3(128, 128), tb, 0, stream>>>(Q, Qtp);
  // 3) R1bf + scaled copies Asc[s]
  scale_r1_kernel<<<4096, 256, 0, stream>>>(R1, R2, lam, R1bf, Asc);
  // 4) T[j2] = Q2-contraction of input
  tprep_kernel<<<8192, 256, 0, stream>>>(input, Q2, T);
  // 5) Dsub[s] = Asc[s] @ R1bf^T   (batched 4 x 2048^3)
  gemm256<float><<<dim3(8, 8, 4), 512, 131072, stream>>>(
      Asc, R1bf, Dsub, 2048, 2048, 2048, 2048, 4194304LL, 4194304LL);
  // 6) rteff = R^T + D
  transadd_kernel<<<dim3(128, 128), tb, 0, stream>>>(R, Dsub, rteff);
  // 7) X1p[:, j2*2048+j1] = T[j2] @ Q1tb^T   (batched 2 x 4096x2048x2048)
  gemm256<u16><<<dim3(8, 16, 2), 512, 131072, stream>>>(
      T, Q1tb, X1p, 4096, 2048, 2048, 4096, 8388608LL, 2048LL);
  // 8) X2 = X1p @ Qtp^T   (4096^3)
  gemm256<u16><<<dim3(16, 16, 1), 512, 131072, stream>>>(
      X1p, Qtp, X2, 4096, 4096, 4096, 4096, 0LL, 0LL);
  // 9) out = X2 @ rteff^T  (4096^3, f32)
  gemm256<float><<<dim3(16, 16, 1), 512, 131072, stream>>>(
      X2, rteff, out, 4096, 4096, 4096, 4096, 0LL, 0LL);
}

// Round 11
// 436.198 us; speedup vs baseline: 1.2590x; 1.2011x over previous
//
#include <hip/hip_runtime.h>
#include <stdint.h>

// KronQRInjectedLinear: out = ((input @ rot) @ Q) @ R_eff.
// Kron structure: rot via 2x4096x2048x2048 batched (T = in·Q2-contract, then @Q1^T);
// D = kron(R1,R2) diag(lam) kron^T reduced to TWO 2048^3 GEMMs:
//   Dsub[s] = c0(s)·De + c1(s)·Do, De=(R1⊙lam_e)@R1^T, Do=(R1⊙lam_o)@R1^T,
//   combo folded into transadd.
// GEMM core: r5's measured-best 8-phase BK=64 2-dbuf schedule (121 us @4096^3).

typedef unsigned short u16;
typedef short bf16x8 __attribute__((ext_vector_type(8)));
typedef float f32x4 __attribute__((ext_vector_type(4)));

__device__ __forceinline__ u16 f2bf(float f) {
  union { float f; uint32_t u; } v; v.f = f;
  return (u16)((v.u + 0x7FFFu + ((v.u >> 16) & 1u)) >> 16);
}

__device__ __forceinline__ void store_out(float* p, float v) { *p = v; }
__device__ __forceinline__ void store_out(u16* p, float v) { *p = f2bf(v); }

__device__ __forceinline__ void gload_lds16(const u16* g, u16* l) {
  __builtin_amdgcn_global_load_lds(
      (__attribute__((address_space(1))) void*)(uintptr_t)g,
      (__attribute__((address_space(3))) void*)l, 16, 0, 0);
}

#define MFMA16(a, b, c) __builtin_amdgcn_mfma_f32_16x16x32_bf16((a), (b), (c), 0, 0, 0)

// ---------------- GEMM: C[M,N] = A[M,K] @ Bt[N,K]^T (batched on z) ----------------
// r5 core: 256x256 tile, 8 waves (2Mx4N), BK=64 K-tiles, 2 LDS double-buffers,
// 8-KB pieces staged 2/phase staggered, derived counted vmcnt(4) at phases 3/7,
// B-frags register-held per K-tile, zero-conflict XOR swizzle, setprio, XCD swizzle.
template <typename OutT>
__global__ __launch_bounds__(512, 2) void gemm256(
    const u16* __restrict__ A, const u16* __restrict__ Bt, OutT* __restrict__ C,
    int M, int N, int K, int ldC, long long sA, long long sC) {
  extern __shared__ __align__(16) u16 smem[];
  u16* ldsA = smem;           // 2 bufs x 16384 elems (64 KB)
  u16* ldsB = smem + 32768;

  const int tid  = (int)threadIdx.x;
  const int lane = tid & 63;
  const int wid  = tid >> 6;
  const int wr   = wid >> 2;       // 0..1 : M half (128 rows)
  const int wc   = wid & 3;        // 0..3 : N quarter (64 cols)

  // XCD-aware bijective swizzle (nwg % 8 == 0 for all our grids)
  const int tilesX = (int)gridDim.x;
  const int tilesXY = tilesX * (int)gridDim.y;
  const int nwg = tilesXY * (int)gridDim.z;
  const int bid = ((int)blockIdx.z * (int)gridDim.y + (int)blockIdx.y) * tilesX + (int)blockIdx.x;
  const int swz = (bid & 7) * (nwg >> 3) + (bid >> 3);
  const int z   = swz / tilesXY;
  const int rem = swz % tilesXY;
  const int brow = (rem / tilesX) << 8;
  const int bcol = (rem % tilesX) << 8;
  A += (size_t)z * sA;
  C += (size_t)z * sC;

  // fragment-read lane constants (swizzled 16B slot is lane-constant)
  const int lr = lane & 15, lg = lane >> 4, h = lr >> 1;
  const int sf = (lg + ((lr & 1) << 2)) ^ h;
  const int abase = wr * 8192 + h * 64 + sf * 8;                    // + frag*512 + ks*4096 + buf*16384
  const int bbase = (wc >> 1) * 8192 + ((wc & 1) * 32 + h) * 64 + sf * 8;

  // staging: linear LDS dest (tid*16B within 8KB piece), inverse-swizzled source
  const int kp   = (tid & 7) ^ ((tid >> 3) & 7);
  const int srow = 2 * (tid >> 3) + (kp >> 2);
  const int scol = (kp & 3) << 3;
  const size_t gA0 = (size_t)(brow + srow) * K + scol;
  const size_t gB0 = (size_t)(bcol + srow) * K + scol;
  const size_t rstep = (size_t)K << 7;     // 128 rows
  const int sdst = wid * 512;

  const int NC = K >> 6;                   // 64-wide K-tiles (even, >= 4)
  const int NI = NC >> 1;

  f32x4 acc[8][4] = {};
  bf16x8 af[4][2], bf[4][2];

#define STG_A(t, rh, ks) gload_lds16(A + gA0 + (rh) * rstep + (size_t)(t) * 64 + (ks) * 32, \
    ldsA + ((t) & 1) * 16384 + (rh) * 8192 + (ks) * 4096 + sdst)
#define STG_B(t, rh, ks) gload_lds16(Bt + gB0 + (rh) * rstep + (size_t)(t) * 64 + (ks) * 32, \
    ldsB + ((t) & 1) * 16384 + (rh) * 8192 + (ks) * 4096 + sdst)
#define VM4 asm volatile("s_waitcnt vmcnt(4)" ::: "memory")
#define VM0 asm volatile("s_waitcnt vmcnt(0)" ::: "memory")

  // Phase: optional ds_reads + 2 staged pieces -> barrier -> lgkm(0) -> 16 MFMA -> tail -> barrier
#define PH(BUF, MH, RDA, RDB01, RDB23, N0, N1, S0, S1, TAIL) do {               \
    const u16* _pa = ldsA + (BUF) * 16384 + abase;                              \
    const u16* _pb = ldsB + (BUF) * 16384 + bbase;                              \
    if (RDA) {                                                                  \
      _Pragma("unroll")                                                         \
      for (int m = 0; m < 4; ++m) {                                             \
        af[m][0] = *(const bf16x8*)(_pa + ((MH) * 4 + m) * 512);                \
        af[m][1] = *(const bf16x8*)(_pa + ((MH) * 4 + m) * 512 + 4096);         \
      }                                                                         \
    }                                                                           \
    if (RDB01) {                                                                \
      bf[0][0] = *(const bf16x8*)(_pb);        bf[0][1] = *(const bf16x8*)(_pb + 4096);       \
      bf[1][0] = *(const bf16x8*)(_pb + 512);  bf[1][1] = *(const bf16x8*)(_pb + 512 + 4096); \
    }                                                                           \
    if (RDB23) {                                                                \
      bf[2][0] = *(const bf16x8*)(_pb + 1024); bf[2][1] = *(const bf16x8*)(_pb + 1024 + 4096); \
      bf[3][0] = *(const bf16x8*)(_pb + 1536); bf[3][1] = *(const bf16x8*)(_pb + 1536 + 4096); \
    }                                                                           \
    S0; S1;                                                                     \
    __builtin_amdgcn_s_barrier();                                               \
    asm volatile("s_waitcnt lgkmcnt(0)" ::: "memory");                          \
    __builtin_amdgcn_sched_barrier(0);                                          \
    __builtin_amdgcn_s_setprio(1);                                              \
    _Pragma("unroll")                                                           \
    for (int m = 0; m < 4; ++m) {                                               \
      acc[(MH) * 4 + m][N0] = MFMA16(af[m][0], bf[N0][0], acc[(MH) * 4 + m][N0]); \
      acc[(MH) * 4 + m][N0] = MFMA16(af[m][1], bf[N0][1], acc[(MH) * 4 + m][N0]); \
      acc[(MH) * 4 + m][N1] = MFMA16(af[m][0], bf[N1][0], acc[(MH) * 4 + m][N1]); \
      acc[(MH) * 4 + m][N1] = MFMA16(af[m][1], bf[N1][1], acc[(MH) * 4 + m][N1]); \
    }                                                                           \
    __builtin_amdgcn_s_setprio(0);                                              \
    TAIL;                                                                       \
    __builtin_amdgcn_sched_barrier(0);                                          \
    __builtin_amdgcn_s_barrier();                                               \
  } while (0)

  // Prologue: A(0), B(0), B(1); wait A(0)+B(0) (leave B(1)'s 4 in flight).
  STG_A(0, 0, 0); STG_A(0, 0, 1); STG_A(0, 1, 0); STG_A(0, 1, 1);
  STG_B(0, 0, 0); STG_B(0, 0, 1); STG_B(0, 1, 0); STG_B(0, 1, 1);
  STG_B(1, 0, 0); STG_B(1, 0, 1); STG_B(1, 1, 0); STG_B(1, 1, 1);
  VM4;
  __builtin_amdgcn_sched_barrier(0);
  __builtin_amdgcn_s_barrier();

  // Steady state. Iter i: compute tiles 2i (buf0), 2i+1 (buf1);
  // stage A(2i+1) @p0-1, B(2i+2) @p2-3, A(2i+2) @p4-5, B(2i+3) @p6-7.
  for (int i = 0; i < NI - 1; ++i) {
    const int tn = 2 * i;
    PH(0, 0, 1, 1, 0, 0, 1, STG_A(tn + 1, 0, 0), STG_A(tn + 1, 0, 1), (void)0);
    PH(0, 0, 0, 0, 1, 2, 3, STG_A(tn + 1, 1, 0), STG_A(tn + 1, 1, 1), (void)0);
    PH(0, 1, 1, 0, 0, 0, 1, STG_B(tn + 2, 0, 0), STG_B(tn + 2, 0, 1), (void)0);
    PH(0, 1, 0, 0, 0, 2, 3, STG_B(tn + 2, 1, 0), STG_B(tn + 2, 1, 1), VM4);
    PH(1, 0, 1, 1, 0, 0, 1, STG_A(tn + 2, 0, 0), STG_A(tn + 2, 0, 1), (void)0);
    PH(1, 0, 0, 0, 1, 2, 3, STG_A(tn + 2, 1, 0), STG_A(tn + 2, 1, 1), (void)0);
    PH(1, 1, 1, 0, 0, 0, 1, STG_B(tn + 3, 0, 0), STG_B(tn + 3, 0, 1), (void)0);
    PH(1, 1, 0, 0, 0, 2, 3, STG_B(tn + 3, 1, 0), STG_B(tn + 3, 1, 1), VM4);
  }
  // Last iter: only A(NC-1) still needed; drain fully at p3.
  {
    PH(0, 0, 1, 1, 0, 0, 1, STG_A(NC - 1, 0, 0), STG_A(NC - 1, 0, 1), (void)0);
    PH(0, 0, 0, 0, 1, 2, 3, STG_A(NC - 1, 1, 0), STG_A(NC - 1, 1, 1), (void)0);
    PH(0, 1, 1, 0, 0, 0, 1, (void)0, (void)0, (void)0);
    PH(0, 1, 0, 0, 0, 2, 3, (void)0, (void)0, VM0);
    PH(1, 0, 1, 1, 0, 0, 1, (void)0, (void)0, (void)0);
    PH(1, 0, 0, 0, 1, 2, 3, (void)0, (void)0, (void)0);
    PH(1, 1, 1, 0, 0, 0, 1, (void)0, (void)0, (void)0);
    PH(1, 1, 0, 0, 0, 2, 3, (void)0, (void)0, (void)0);
  }

#undef PH
#undef STG_A
#undef STG_B
#undef VM4
#undef VM0

  // C/D layout per 16x16 frag: col = lane&15, row = (lane>>4)*4 + j
#pragma unroll
  for (int m = 0; m < 8; ++m) {
    const int r0 = brow + wr * 128 + m * 16 + lg * 4;
#pragma unroll
    for (int n = 0; n < 4; ++n) {
      const int cc = bcol + wc * 64 + n * 16 + lr;
#pragma unroll
      for (int j = 0; j < 4; ++j)
        store_out(&C[(size_t)(r0 + j) * ldC + cc], acc[m][n][j]);
    }
  }
}

// ---------------- tiled transpose: out[c][r] = bf16(in[r][c]) ----------------
__global__ void trans_kernel(const float* __restrict__ in, u16* __restrict__ out, int n) {
  __shared__ float t[32][33];
  const int bx = (int)blockIdx.x * 32, by = (int)blockIdx.y * 32;
  const int x = (int)threadIdx.x, y0 = (int)threadIdx.y;
#pragma unroll
  for (int dy = 0; dy < 32; dy += 8)
    t[y0 + dy][x] = in[(size_t)(bx + y0 + dy) * n + by + x];
  __syncthreads();
#pragma unroll
  for (int dy = 0; dy < 32; dy += 8)
    out[(size_t)(by + y0 + dy) * n + bx + x] = f2bf(t[x][y0 + dy]);
}

// Qtp[c][perm(r)] = bf16(Q[r][c]); perm(r) = ((r&1)<<11)|(r>>1)
__global__ void transperm_kernel(const float* __restrict__ in, u16* __restrict__ out) {
  __shared__ float t[32][33];
  const int bx = (int)blockIdx.x * 32, by = (int)blockIdx.y * 32;
  const int x = (int)threadIdx.x, y0 = (int)threadIdx.y;
#pragma unroll
  for (int dy = 0; dy < 32; dy += 8)
    t[y0 + dy][x] = in[(size_t)(bx + y0 + dy) * 4096 + by + x];
  __syncthreads();
  const int r = bx + x;
  const int cp = ((r & 1) << 11) | (r >> 1);
#pragma unroll
  for (int dy = 0; dy < 32; dy += 8)
    out[(size_t)(by + y0 + dy) * 4096 + cp] = f2bf(t[x][y0 + dy]);
}

// rteff[i][j] = bf16(R[j][i] + D[i][j]);
// D[i][j] = c0(i&1,j&1)*De[i>>1][j>>1] + c1(i&1,j&1)*Do[i>>1][j>>1]
__global__ void transadd_kernel(const float* __restrict__ R, const float* __restrict__ Dsub,
                                const float* __restrict__ R2, u16* __restrict__ out) {
  __shared__ float t[32][33];
  const int bx = (int)blockIdx.x * 32, by = (int)blockIdx.y * 32;
  const int x = (int)threadIdx.x, y0 = (int)threadIdx.y;
#pragma unroll
  for (int dy = 0; dy < 32; dy += 8)
    t[y0 + dy][x] = R[(size_t)(bx + y0 + dy) * 4096 + by + x];
  __syncthreads();
  const float r20 = R2[0], r21 = R2[1], r22 = R2[2], r23 = R2[3];
  const int j = bx + x;
  const float cj0 = (j & 1) ? r22 : r20;   // R2[j2][0]
  const float cj1 = (j & 1) ? r23 : r21;   // R2[j2][1]
#pragma unroll
  for (int dy = 0; dy < 32; dy += 8) {
    const int i = by + y0 + dy;
    const float ci0 = (i & 1) ? r22 : r20;
    const float ci1 = (i & 1) ? r23 : r21;
    const size_t o = ((size_t)(i >> 1) << 11) + (j >> 1);
    const float d = ci0 * cj0 * Dsub[o] + ci1 * cj1 * Dsub[o + 4194304];
    out[(size_t)i * 4096 + j] = f2bf(t[x][y0 + dy] + d);
  }
}

// R1bf = bf16(R1); Ae = bf16(R1 .* lam_e); Ao = bf16(R1 .* lam_o)
__global__ void scale_r1_kernel(const float* __restrict__ R1, const float* __restrict__ lam,
                                u16* __restrict__ R1bf, u16* __restrict__ Ae,
                                u16* __restrict__ Ao) {
  const int idx = (int)blockIdx.x * 256 + (int)threadIdx.x;   // over 2048*512
  const int i1 = idx >> 9, k1 = (idx & 511) << 2;
  const float4 r1 = *(const float4*)(R1 + (size_t)i1 * 2048 + k1);
  const float4 l0 = *(const float4*)(lam + 2 * k1);
  const float4 l1 = *(const float4*)(lam + 2 * k1 + 4);
  const size_t off = (size_t)i1 * 2048 + k1;
  ushort4 rb, eb, ob;
  rb.x = f2bf(r1.x); rb.y = f2bf(r1.y); rb.z = f2bf(r1.z); rb.w = f2bf(r1.w);
  eb.x = f2bf(r1.x * l0.x); eb.y = f2bf(r1.y * l0.z);
  eb.z = f2bf(r1.z * l1.x); eb.w = f2bf(r1.w * l1.z);
  ob.x = f2bf(r1.x * l0.y); ob.y = f2bf(r1.y * l0.w);
  ob.z = f2bf(r1.z * l1.y); ob.w = f2bf(r1.w * l1.w);
  *(ushort4*)(R1bf + off) = rb;
  *(ushort4*)(Ae + off) = eb;
  *(ushort4*)(Ao + off) = ob;
}

// T[j2][s][k1] = bf16(in[s][2k1]*Q2[0][j2] + in[s][2k1+1]*Q2[1][j2])
__global__ void tprep_kernel(const float* __restrict__ in, const float* __restrict__ Q2,
                             u16* __restrict__ T) {
  const int idx = (int)blockIdx.x * 256 + (int)threadIdx.x;   // over 4096*512
  const int s = idx >> 9, k1 = (idx & 511) << 2;
  const float4 a = *(const float4*)(in + (size_t)s * 4096 + 2 * k1);
  const float4 b = *(const float4*)(in + (size_t)s * 4096 + 2 * k1 + 4);
  const float e[4] = {a.x, a.z, b.x, b.z};
  const float o[4] = {a.y, a.w, b.y, b.w};
  const float q00 = Q2[0], q01 = Q2[1], q10 = Q2[2], q11 = Q2[3];
  ushort4 t0, t1;
  t0.x = f2bf(e[0] * q00 + o[0] * q10); t1.x = f2bf(e[0] * q01 + o[0] * q11);
  t0.y = f2bf(e[1] * q00 + o[1] * q10); t1.y = f2bf(e[1] * q01 + o[1] * q11);
  t0.z = f2bf(e[2] * q00 + o[2] * q10); t1.z = f2bf(e[2] * q01 + o[2] * q11);
  t0.w = f2bf(e[3] * q00 + o[3] * q10); t1.w = f2bf(e[3] * q01 + o[3] * q11);
  *(ushort4*)(T + (size_t)s * 2048 + k1) = t0;
  *(ushort4*)(T + 8388608 + (size_t)s * 2048 + k1) = t1;
}

extern "C" void kernel_launch(void* const* d_in, const int* in_sizes, int n_in,
                              void* d_out, int out_size, void* d_ws, size_t ws_size,
                              hipStream_t stream) {
  const float* input = (const float*)d_in[0];
  const float* Q     = (const float*)d_in[1];
  const float* R     = (const float*)d_in[2];
  const float* Q1    = (const float*)d_in[3];
  const float* Q2    = (const float*)d_in[4];
  const float* R1    = (const float*)d_in[5];
  const float* R2    = (const float*)d_in[6];
  const float* lam   = (const float*)d_in[7];
  float* out = (float*)d_out;

  const size_t MB = 1024ull * 1024ull;
  char* ws = (char*)d_ws;
  u16* R1bf  = (u16*)(ws + 0 * MB);
  u16* Ae    = (u16*)(ws + 8 * MB);     // adjacent planes: batched A stride 4194304 elems
  u16* Ao    = (u16*)(ws + 16 * MB);
  u16* Q1tb  = (u16*)(ws + 24 * MB);
  u16* T     = (u16*)(ws + 32 * MB);    // 2 planes of 16MB
  u16* Qtp   = (u16*)(ws + 64 * MB);
  u16* rteff = (u16*)(ws + 96 * MB);
  u16* X1p   = (u16*)(ws + 128 * MB);   // needs ws_size >= 160 MB
  u16* X2    = (u16*)(ws + 8 * MB);     // reuses Ae/Ao/Q1tb/T-head (all dead by step 8)
  float* Dsub = (float*)d_out;          // 2 x 2048^2 f32 (32MB), consumed by transadd

  {
    void (*pf)(const u16*, const u16*, float*, int, int, int, int, long long, long long) = gemm256<float>;
    void (*pb)(const u16*, const u16*, u16*, int, int, int, int, long long, long long)   = gemm256<u16>;
    (void)hipFuncSetAttribute((const void*)pf, hipFuncAttributeMaxDynamicSharedMemorySize, 131072);
    (void)hipFuncSetAttribute((const void*)pb, hipFuncAttributeMaxDynamicSharedMemorySize, 131072);
  }

  const dim3 tb(32, 8);
  // 1) Q1tb = bf16(Q1^T)
  trans_kernel<<<dim3(64, 64), tb, 0, stream>>>(Q1, Q1tb, 2048);
  // 2) Qtp = permuted bf16(Q^T)
  transperm_kernel<<<dim3(128, 128), tb, 0, stream>>>(Q, Qtp);
  // 3) R1bf + Ae/Ao scaled copies
  scale_r1_kernel<<<4096, 256, 0, stream>>>(R1, lam, R1bf, Ae, Ao);
  // 4) T[j2] = Q2-contraction of input
  tprep_kernel<<<8192, 256, 0, stream>>>(input, Q2, T);
  // 5) {De,Do} = {Ae,Ao} @ R1bf^T   (batched 2 x 2048^3)
  gemm256<float><<<dim3(8, 8, 2), 512, 131072, stream>>>(
      Ae, R1bf, Dsub, 2048, 2048, 2048, 2048, 4194304LL, 4194304LL);
  // 6) rteff = R^T + (c0*De + c1*Do expanded via kron indices)
  transadd_kernel<<<dim3(128, 128), tb, 0, stream>>>(R, Dsub, R2, rteff);
  // 7) X1p[:, j2*2048+j1] = T[j2] @ Q1tb^T   (batched 2 x 4096x2048x2048)
  gemm256<u16><<<dim3(8, 16, 2), 512, 131072, stream>>>(
      T, Q1tb, X1p, 4096, 2048, 2048, 4096, 8388608LL, 2048LL);
  // 8) X2 = X1p @ Qtp^T   (4096^3)
  gemm256<u16><<<dim3(16, 16, 1), 512, 131072, stream>>>(
      X1p, Qtp, X2, 4096, 4096, 4096, 4096, 0LL, 0LL);
  // 9) out = X2 @ rteff^T  (4096^3, f32)
  gemm256<float><<<dim3(16, 16, 1), 512, 131072, stream>>>(
      X2, rteff, out, 4096, 4096, 4096, 4096, 0LL, 0LL);
}